// Round 8
// baseline (259.848 us; speedup 1.0000x reference)
//
#include <hip/hip_runtime.h>

// SNN forward scan: B=64, N=1024, T=512. Row = (b*N+n), x[row*512 + t].
//
// R8: deep-pipeline wave specialization. R7 (83us) was latency-bound by
// Little's law: load waves issued one 16-KiB burst per ~5us chunk period
// then idled at barriers -> ~1-2 KB avg in flight per CU vs ~9 KB needed
// for fair-share BW. Changes:
//  * 2 load waves on alternating chunks: each chunk's loads issued 2
//    periods before staging (vmcnt slack, 2x outstanding bytes).
//  * compute reads the chunk as 16x ds_read_b128 into regs BEFORE the
//    64-step chain (LDS latency paid once per chunk, not per step).
//    STRIDE=68 floats: 16B-aligned rows, conflict-free b128 groups.
//  * spikes packed as bytes in LDS (u32 = 4 spikes): out-buffer 4x
//    smaller -> double-buffered -> ONE lgkm-only barrier per chunk.
//    Store wave (mostly idle) unpacks bytes->float4 and stores 256 B/row
//    contiguous (keeps R7's full-line writes: WRITE_SIZE == output size).
//  LDS = 45 KB -> 3 blocks/CU = 12 waves/CU.
//
// Numerics: BIT-EXACT vs float32 NumPy reference (0/1 threshold output —
// one ulp flip cascades). __fmul_rn/__fadd_rn + contract(off).
#pragma clang fp contract(off)

#define ROWS    64                    // rows per block (1 compute wave)
#define T_LEN   512
#define CHUNK   64                    // timesteps per tile (256 B/row contiguous)
#define NCHUNK  (T_LEN / CHUNK)       // 8
#define STRIDE  68                    // floats/row in inbuf: 17 float4, bank-clean
#define WSTRIDE 20                    // u32/row in packed spike buffer (16 + pad)
#define NV      16                    // float4 per io-lane per chunk
#define NPARAM  1024

// lgkmcnt(0)-only barrier: LDS visibility without the vmcnt(0) drain.
#define BARRIER() asm volatile("s_waitcnt lgkmcnt(0)\n\ts_barrier" ::: "memory")

__global__ __launch_bounds__(256) void snn_fwd(
    const float* __restrict__ x,
    const float* __restrict__ beta,
    const float* __restrict__ p,
    const float* __restrict__ bparam,
    float* __restrict__ out)
{
    __shared__ __align__(16) float        inbuf[2][ROWS * STRIDE];  // 34,816 B
    __shared__ __align__(16) unsigned int outw [2][ROWS * WSTRIDE]; // 10,240 B

    const int tid     = threadIdx.x;
    const int wid     = tid >> 6;   // 0=compute, 1=load(even), 2=load(odd), 3=store
    const int lane    = tid & 63;
    const int rowBase = blockIdx.x * ROWS;

    const float4* __restrict__ xv = (const float4*)x;  // row stride 128 float4
    float4* __restrict__ ov       = (float4*)out;

    // io mapping: lane = r4*16 + t16. One instr: rows {r4+4*it}, 256 B
    // contiguous per row (16 float4). Chunk k adds k*NV float4.
    const int t16 = lane & 15;
    const int r4  = lane >> 4;
    const int gq  = (rowBase + r4) * (T_LEN / 4) + t16;  // float4 units
    const int lf  = r4 * STRIDE + t16 * 4;               // float units

    // compute state
    float mem = 0.0f, refac = 2.0f, a = 0.0f, vth = 1.0f, ps = 0.0f;
    float beta_c = 0.f, p_c = 0.f, b_c = 0.f;

    if (wid == 0) {
        const int n = (rowBase + lane) & (NPARAM - 1);
        beta_c = fminf(fmaxf(beta[n], 0.001f), 0.999f);
        p_c    = fminf(fabsf(p[n]), 0.999f);
        b_c    = fminf(fmaxf(fabsf(bparam[n]), 0.001f), 1.0f);
    }

    auto step = [&](float xt) -> float {
        refac = (ps > 0.0f) ? 0.0f : refac;           // spike-triggered reset
        const float ic = (refac < 2.0f) ? 0.0f : xt;  // refractory input mask
        refac += 1.0f;
        const float nm   = __fadd_rn(__fmul_rn(mem, beta_c), ic);  // integrate
        const float diff = __fsub_rn(nm, vth);
        const float s    = (diff > 0.0f) ? 1.0f : 0.0f;
        mem = (diff > 0.0f) ? 0.0f : nm;              // reset-to-zero on spike
        a   = __fadd_rn(__fmul_rn(p_c, a), s);        // adaptation
        vth = __fadd_rn(1.0f, __fmul_rn(b_c, a));     // adaptive threshold
        ps  = s;
        return s;
    };

    float4 ld[NV];  // load wave's register pipeline (its chunk, 2 periods early)

    auto loadChunk = [&](int k) {
        const int base = gq + k * NV;
        #pragma unroll
        for (int it = 0; it < NV; ++it)
            ld[it] = xv[base + it * 4 * (T_LEN / 4)];  // +4 rows per it
    };
    auto stage = [&](int buf) {  // b128 writes, conflict-free (STRIDE=68)
        #pragma unroll
        for (int it = 0; it < NV; ++it)
            *(float4*)&inbuf[buf][lf + it * 4 * STRIDE] = ld[it];
    };
    auto drain = [&](int k) {    // packed bytes -> float4, 256 B/row stores
        const int buf  = k & 1;
        const int base = gq + k * NV;
        #pragma unroll
        for (int it = 0; it < NV; ++it) {
            const unsigned int u = outw[buf][(r4 + 4 * it) * WSTRIDE + t16];
            float4 f;
            f.x = (u & 0x000000ffu) ? 1.0f : 0.0f;
            f.y = (u & 0x0000ff00u) ? 1.0f : 0.0f;
            f.z = (u & 0x00ff0000u) ? 1.0f : 0.0f;
            f.w = (u & 0xff000000u) ? 1.0f : 0.0f;
            ov[base + it * 4 * (T_LEN / 4)] = f;
        }
    };

    // preamble: chunk 0 staged; chunks 1,2 in regs (in flight across barrier)
    if (wid == 1) {            // even-parity chunks: 0,2,4,6
        loadChunk(0);
        stage(0);
        loadChunk(2);
    } else if (wid == 2) {     // odd-parity chunks: 1,3,5,7
        loadChunk(1);
    }
    BARRIER();

    const int cb4 = lane * STRIDE;   // compute lane's inbuf row (floats)
    const int wb  = lane * WSTRIDE;  // compute lane's outw row (u32)

    #pragma unroll 1
    for (int k = 0; k < NCHUNK; ++k) {
        const int cur = k & 1;
        if (wid == 0) {
            // batch-read whole chunk (16 b128), then pure-VALU 64-step chain
            float4 xq[16];
            #pragma unroll
            for (int c = 0; c < 16; ++c)
                xq[c] = *(const float4*)&inbuf[cur][cb4 + 4 * c];
            unsigned int wpk[16];
            #pragma unroll
            for (int c = 0; c < 16; ++c) {
                const unsigned sx = (unsigned)step(xq[c].x);
                const unsigned sy = (unsigned)step(xq[c].y);
                const unsigned sz = (unsigned)step(xq[c].z);
                const unsigned sw = (unsigned)step(xq[c].w);
                wpk[c] = sx | (sy << 8) | (sz << 16) | (sw << 24);
            }
            #pragma unroll
            for (int q = 0; q < 4; ++q)
                *(uint4*)&outw[cur][wb + 4 * q] =
                    make_uint4(wpk[4*q], wpk[4*q+1], wpk[4*q+2], wpk[4*q+3]);
        } else if (wid == 1 || wid == 2) {
            // the wave whose parity matches chunk k+1 stages it, then issues
            // its next chunk's loads (k+3) -> every chunk loaded 2 periods early
            if (((k + 1) & 1) == (wid - 1)) {
                if (k + 1 < NCHUNK) stage((k + 1) & 1);
                if (k + 3 < NCHUNK) loadChunk(k + 3);
            }
        } else {
            if (k > 0) drain(k - 1);  // outw[(k-1)&1], barrier-separated
        }
        BARRIER();
    }
    if (wid == 3) drain(NCHUNK - 1);
}

extern "C" void kernel_launch(void* const* d_in, const int* in_sizes, int n_in,
                              void* d_out, int out_size, void* d_ws, size_t ws_size,
                              hipStream_t stream) {
    const float* x    = (const float*)d_in[0];
    const float* beta = (const float*)d_in[1];
    const float* p    = (const float*)d_in[2];
    const float* b    = (const float*)d_in[3];
    float* out        = (float*)d_out;

    const int BN = 64 * 1024;  // rows
    snn_fwd<<<dim3(BN / ROWS), dim3(256), 0, stream>>>(x, beta, p, b, out);
}